// Round 14
// baseline (106.549 us; speedup 1.0000x reference)
//
#include <hip/hip_runtime.h>
#include <cmath>

#define BB 8
#define CC 128
#define NN 16384
#define HH 4
#define NC1 128                  // fuse1 chunks per batch (128 n each)
#define NC2 128                  // pass2 chunks per batch (128 n each)

typedef __attribute__((ext_vector_type(8))) short bf16x8;
typedef __attribute__((ext_vector_type(4))) float f32x4;

#define MFMA(a, b, c) __builtin_amdgcn_mfma_f32_16x16x32_bf16(a, b, c, 0, 0, 0)

// fp32 -> bf16 (RNE)
__device__ __forceinline__ unsigned short f2b(float f) {
  union { float f; unsigned u; } v; v.f = f;
  unsigned r = v.u + 0x7FFFu + ((v.u >> 16) & 1u);
  return (unsigned short)(r >> 16);
}

// KT/VT layout: [c][n] bf16, 144 B/row stride, XOR-swizzle on 16B blocks
__device__ __forceinline__ int kt_byte(int c, int n) {
  return c * 144 + ((((n >> 3) ^ (c & 7)) << 4) | ((n & 7) << 1));
}

// ---------------------------------------------------------------------------
// K0: convert Wq,Wk,Wv,Wo fp32[128][128] -> bf16 (same layout)
// ---------------------------------------------------------------------------
__global__ void k_prep(const float* __restrict__ Wq, const float* __restrict__ Wk,
                       const float* __restrict__ Wv, const float* __restrict__ Wo,
                       unsigned short* __restrict__ Wb) {
  const int idx = blockIdx.x * 256 + threadIdx.x;   // < 65536
  const int which = idx >> 14;
  const float* src = (which == 0) ? Wq : (which == 1) ? Wk : (which == 2) ? Wv : Wo;
  Wb[idx] = f2b(src[idx & 16383]);
}

// ---------------------------------------------------------------------------
// K1: x fp32 [b][c][n] -> xF bf16 strips [b][cblk=c/8][n][8c].
// An MFMA B-fragment is then ONE 16B load at ((b*16+cblk)*NN + n)*8.
// 256 blocks (1/CU), 1024 thr. Reads: wave-wide 1 KB x2 per c-row (fully
// linear). LDS bounce: 64 c x 512 n fp32 (128 KB). Strip writes: 1 KB-contig.
// ---------------------------------------------------------------------------
__global__ __launch_bounds__(1024)
void k_xpose(const float* __restrict__ x, unsigned short* __restrict__ xF) {
  extern __shared__ char lds[];          // 64 x 512 fp32 = 131072 B
  float* XS = (float*)lds;
  const int tid = threadIdx.x;
  const int lane = tid & 63;
  const int w = tid >> 6;                // 0..15
  const int b = blockIdx.y;
  const int n0 = blockIdx.x * 512;

  for (int g = 0; g < 2; ++g) {          // c-halves: c = g*64 + 0..63
    if (g) __syncthreads();              // prior reads of XS done before rewrite
    // stage: wave w owns c-local rows w*4..w*4+4; each row = 2x wave-wide 1 KB
#pragma unroll
    for (int r = 0; r < 4; ++r) {
      const int cl = w * 4 + r;
      const float* src = x + ((size_t)b * CC + g * 64 + cl) * NN + n0;
      const float4 v0 = *(const float4*)(src + lane * 4);
      const float4 v1 = *(const float4*)(src + 256 + lane * 4);
      *(float4*)(XS + cl * 512 + lane * 4) = v0;
      *(float4*)(XS + cl * 512 + 256 + lane * 4) = v1;
    }
    __syncthreads();
    // transpose-read: thread -> (cblk2 = tid>>9, n = tid&511); 4 cblks each.
    // LDS reads: lanes n-consecutive -> banks 0..31 x2, conflict-free.
    const int n = tid & 511;
    const int cblk2 = tid >> 9;          // 0..1
#pragma unroll
    for (int cb = 0; cb < 4; ++cb) {
      const int cbl = cb * 2 + cblk2;    // local cblk 0..7
      bf16x8 pk;
#pragma unroll
      for (int cc = 0; cc < 8; ++cc)
        ((unsigned short*)&pk)[cc] = f2b(XS[(cbl * 8 + cc) * 512 + n]);
      *(bf16x8*)(xF + (((size_t)b * 16 + g * 8 + cbl) * NN + n0 + n) * 8) = pk;
    }
  }
}

// ---------------------------------------------------------------------------
// K2: K/V proj + per-head LN + partial K^T V. NO x staging: proj B-fragments
// load directly from xF strips (16B/lane coalesced, L3-hot).
// Grid 128x8 = 1024 blocks; LDS = KT+VT = 36864 -> 4 blocks/CU, 8 waves/SIMD.
// Roles: proj (head = w>>1, K/V = w&1); kv (head = w>>1, 32-n half = w&1)
// ---------------------------------------------------------------------------
__global__ __launch_bounds__(512, 4)
void k_fuse1(const unsigned short* __restrict__ xF,
             const unsigned short* __restrict__ Wkb, const unsigned short* __restrict__ Wvb,
             const float* __restrict__ bk, const float* __restrict__ bv,
             const float* __restrict__ gK, const float* __restrict__ bK,
             const float* __restrict__ gV, const float* __restrict__ bV,
             float* __restrict__ kvp) {
  extern __shared__ char lds[];
  char* KT = lds;                       // 18432 B
  char* VT = lds + 18432;               // 18432 B
  float* KVS = (float*)lds;             // 32 KB, overlays KT/VT at the end

  const int tid = threadIdx.x;
  const int lane = tid & 63;
  const int w = tid >> 6;               // 0..7
  const int b = blockIdx.y;
  const int bx = blockIdx.x;            // 0..127 (128-n chunk)
  const int l15 = lane & 15, l4 = lane >> 4;

  const int ph = w >> 1, pp = w & 1;    // proj: head, K/V
  const int kh = w >> 1, khalf = w & 1; // kv: head, 32-n half

  // W fragments: row = l15 (c_out), k = ks*32 + l4*8 + j
  const unsigned short* Wsrc = pp ? Wvb : Wkb;
  bf16x8 wf[2][4];
#pragma unroll
  for (int mf = 0; mf < 2; ++mf)
#pragma unroll
    for (int ks = 0; ks < 4; ++ks)
      wf[mf][ks] = *(const bf16x8*)(Wsrc + (ph * 32 + mf * 16 + l15) * 128 + ks * 32 + l4 * 8);

  float bias[2][4], gam[2][4], bet[2][4];
  {
    const float* bsrc = pp ? bv : bk;
    const float* gsrc = pp ? gV : gK;
    const float* esrc = pp ? bV : bK;
#pragma unroll
    for (int mf = 0; mf < 2; ++mf)
#pragma unroll
      for (int r = 0; r < 4; ++r) {
        const int cg = ph * 32 + mf * 16 + l4 * 4 + r;
        bias[mf][r] = bsrc[cg]; gam[mf][r] = gsrc[cg]; bet[mf][r] = esrc[cg];
      }
  }

  f32x4 kvacc[2][2];
#pragma unroll
  for (int i = 0; i < 2; ++i)
#pragma unroll
    for (int j = 0; j < 2; ++j) kvacc[i][j] = (f32x4){0.f, 0.f, 0.f, 0.f};

  const unsigned short* xb = xF + (size_t)b * 16 * NN * 8;

  for (int t = 0; t < 2; ++t) {
    const int nt = bx * 128 + t * 64;
    char* DST = pp ? VT : KT;
#pragma unroll
    for (int nf = 0; nf < 4; ++nf) {
      const int n = nt + nf * 16 + l15;
      f32x4 a0 = (f32x4){0.f, 0.f, 0.f, 0.f}, a1 = (f32x4){0.f, 0.f, 0.f, 0.f};
#pragma unroll
      for (int ks = 0; ks < 4; ++ks) {
        const bf16x8 xf = *(const bf16x8*)(xb + ((size_t)(ks * 4 + l4) * NN + n) * 8);
        a0 = MFMA(wf[0][ks], xf, a0);
        a1 = MFMA(wf[1][ks], xf, a1);
      }
#pragma unroll
      for (int r = 0; r < 4; ++r) { a0[r] += bias[0][r]; a1[r] += bias[1][r]; }
      float s = 0.f, ss = 0.f;
#pragma unroll
      for (int r = 0; r < 4; ++r) {
        s += a0[r] + a1[r];
        ss += a0[r] * a0[r] + a1[r] * a1[r];
      }
      s += __shfl_xor(s, 16); ss += __shfl_xor(ss, 16);
      s += __shfl_xor(s, 32); ss += __shfl_xor(ss, 32);
      const float mu = s * (1.f / 32.f);
      const float var = ss * (1.f / 32.f) - mu * mu;
      const float rstd = rsqrtf(var + 1e-5f);
      const int nloc = nf * 16 + l15;
#pragma unroll
      for (int r = 0; r < 4; ++r) {
        const int c0k = ph * 32 + l4 * 4 + r;
        *(unsigned short*)(DST + kt_byte(c0k, nloc)) =
            f2b((a0[r] - mu) * rstd * gam[0][r] + bet[0][r]);
        const int c1k = ph * 32 + 16 + l4 * 4 + r;
        *(unsigned short*)(DST + kt_byte(c1k, nloc)) =
            f2b((a1[r] - mu) * rstd * gam[1][r] + bet[1][r]);
      }
    }
    __syncthreads();

    // kv partial += K^T V over this wave's 32-n half of the 64-n sub-tile
#pragma unroll
    for (int mf = 0; mf < 2; ++mf) {
      const int ck = kh * 32 + mf * 16 + l15;
      const bf16x8 ka = *(const bf16x8*)(KT + ck * 144 + (((khalf * 4 + l4) ^ (ck & 7)) << 4));
#pragma unroll
      for (int ef = 0; ef < 2; ++ef) {
        const int cv = kh * 32 + ef * 16 + l15;
        const bf16x8 vb = *(const bf16x8*)(VT + cv * 144 + (((khalf * 4 + l4) ^ (cv & 7)) << 4));
        kvacc[mf][ef] = MFMA(ka, vb, kvacc[mf][ef]);
      }
    }
    __syncthreads();   // KT/VT safe to overwrite (or overlay in epilogue)
  }

  // epilogue: KVS[w][1024] (overlays KT/VT), pair-reduce khalf, 16 KB dump
#pragma unroll
  for (int mf = 0; mf < 2; ++mf)
#pragma unroll
    for (int ef = 0; ef < 2; ++ef)
#pragma unroll
      for (int r = 0; r < 4; ++r) {
        const int d = mf * 16 + l4 * 4 + r, e = ef * 16 + l15;
        KVS[w * 1024 + d * 32 + e] = kvacc[mf][ef][r];
      }
  __syncthreads();
  {
    float* og = kvp + ((size_t)(b * NC1 + bx)) * 4096;
#pragma unroll
    for (int i = 0; i < 2; ++i) {
      const int off = i * 2048 + tid * 4;          // 0..4095 = h*1024 + q
      const int h = off >> 10, q = off & 1023;
      const f32x4 v0 = *(const f32x4*)(KVS + (2 * h) * 1024 + q);
      const f32x4 v1 = *(const f32x4*)(KVS + (2 * h + 1) * 1024 + q);
      *(f32x4*)(og + off) = v0 + v1;
    }
  }
}

// ---------------------------------------------------------------------------
// K3a: partial reduce: block (b,h,s): sum over 16 bx slots
// ---------------------------------------------------------------------------
__global__ void k_reduceA(const float* __restrict__ kvp, float* __restrict__ p2) {
  const int blk = blockIdx.x;           // (b*4+h)*8 + s, 256 blocks
  const int s = blk & 7, h = (blk >> 3) & 3, b = blk >> 5;
  const int t = threadIdx.x;            // 256 threads, float4 each
  f32x4 acc = (f32x4){0.f, 0.f, 0.f, 0.f};
  for (int i = 0; i < 16; ++i) {
    const int bx = s * 16 + i;
    acc += *(const f32x4*)(kvp + ((size_t)(b * NC1 + bx)) * 4096 + h * 1024 + t * 4);
  }
  *(f32x4*)(p2 + (size_t)blk * 1024 + t * 4) = acc;
}

// ---------------------------------------------------------------------------
// K3b: final reduce over s, scale, store kvT[b][h][e][d] bf16
// ---------------------------------------------------------------------------
__global__ void k_reduceB(const float* __restrict__ p2, unsigned short* __restrict__ kvT,
                          const float scale) {
  const int bh = blockIdx.x;            // b*4+h, 32 blocks
  const int t = threadIdx.x;            // 256 threads
  f32x4 acc = (f32x4){0.f, 0.f, 0.f, 0.f};
  for (int s = 0; s < 8; ++s)
    acc += *(const f32x4*)(p2 + ((size_t)bh * 8 + s) * 1024 + t * 4);
#pragma unroll
  for (int j = 0; j < 4; ++j) {
    const int i = t * 4 + j;
    const int d = i >> 5, e = i & 31;
    kvT[(size_t)bh * 1024 + e * 32 + d] = f2b(acc[j] * scale);
  }
}

// ---------------------------------------------------------------------------
// K4: Q proj + attn + out-GEMM. NO x staging: q-proj fragments load directly
// from xF strips. Grid 128x8; LDS = QS+AS = 32768 -> 4 blocks/CU, 8 w/SIMD.
// ---------------------------------------------------------------------------
__global__ __launch_bounds__(512, 4)
void k_pass2(const unsigned short* __restrict__ xF,
             const unsigned short* __restrict__ Wqb, const float* __restrict__ bq,
             const unsigned short* __restrict__ kvT,
             const unsigned short* __restrict__ Wob, const float* __restrict__ bo,
             float* __restrict__ out) {
  extern __shared__ char lds[];
  char* QS = lds;            // 16384  q as [n][c]
  char* AS = lds + 16384;    // 16384  attn out as [n][c']

  const int tid = threadIdx.x;
  const int lane = tid & 63;
  const int w = tid >> 6;
  const int b = blockIdx.y;
  const int l15 = lane & 15, l4 = lane >> 4;
  const int h = w >> 1, half = w & 1;

  // kv A-fragments (row = e, k = d) from global bf16 kvT[b][h][e][d]
  bf16x8 kvf[2];
#pragma unroll
  for (int mf = 0; mf < 2; ++mf)
    kvf[mf] = *(const bf16x8*)(kvT + (((size_t)b * HH + h) * 32 + mf * 16 + l15) * 32 + l4 * 8);
  bf16x8 wq[4], wo[4];
#pragma unroll
  for (int ks = 0; ks < 4; ++ks) {
    wq[ks] = *(const bf16x8*)(Wqb + (w * 16 + l15) * 128 + ks * 32 + l4 * 8);
    wo[ks] = *(const bf16x8*)(Wob + (w * 16 + l15) * 128 + ks * 32 + l4 * 8);
  }
  float bq_r[4], bo_r[4];
#pragma unroll
  for (int r = 0; r < 4; ++r) {
    bq_r[r] = bq[w * 16 + l4 * 4 + r];
    bo_r[r] = bo[w * 16 + l4 * 4 + r];
  }

  const unsigned short* xb = xF + (size_t)b * 16 * NN * 8;
  float* ob = out + (size_t)b * CC * NN;

  for (int it = 0; it < 2; ++it) {
    const int n0 = blockIdx.x * 128 + it * 64;

    // Phase B: q-GEMM, D[c][n], c-slice = w*16; B-fragments direct from xF
    f32x4 qa[4];
#pragma unroll
    for (int nf = 0; nf < 4; ++nf) qa[nf] = (f32x4){0.f, 0.f, 0.f, 0.f};
#pragma unroll
    for (int ks = 0; ks < 4; ++ks)
#pragma unroll
      for (int nf = 0; nf < 4; ++nf) {
        const int n = n0 + nf * 16 + l15;
        const bf16x8 xf = *(const bf16x8*)(xb + ((size_t)(ks * 4 + l4) * NN + n) * 8);
        qa[nf] = MFMA(wq[ks], xf, qa[nf]);
      }
#pragma unroll
    for (int nf = 0; nf < 4; ++nf) {
      const int n = nf * 16 + l15;
      const int c0 = w * 16 + l4 * 4;
      unsigned long long pk = 0;
#pragma unroll
      for (int r = 0; r < 4; ++r)
        pk |= (unsigned long long)f2b(qa[nf][r] + bq_r[r]) << (16 * r);
      *(unsigned long long*)(QS + n * 256 + (((c0 >> 3) ^ (n & 15)) << 4) + ((c0 & 7) << 1)) = pk;
    }
    __syncthreads();

    // Phase C: attn D[e][n] = kv(as A) * q(as B), per (head, n-half)
    f32x4 aa[2][2];
#pragma unroll
    for (int i = 0; i < 2; ++i)
#pragma unroll
      for (int j = 0; j < 2; ++j) aa[i][j] = (f32x4){0.f, 0.f, 0.f, 0.f};
    bf16x8 qf[2];
#pragma unroll
    for (int nf = 0; nf < 2; ++nf) {
      const int n = half * 32 + nf * 16 + l15;
      const int cq = h * 32 + l4 * 8;
      qf[nf] = *(const bf16x8*)(QS + n * 256 + ((((cq >> 3)) ^ (n & 15)) << 4));
    }
#pragma unroll
    for (int mf = 0; mf < 2; ++mf)
#pragma unroll
      for (int nf = 0; nf < 2; ++nf) aa[mf][nf] = MFMA(kvf[mf], qf[nf], aa[mf][nf]);
#pragma unroll
    for (int mf = 0; mf < 2; ++mf)
#pragma unroll
      for (int nf = 0; nf < 2; ++nf) {
        const int n = half * 32 + nf * 16 + l15;
        const int e0 = h * 32 + mf * 16 + l4 * 4;
        unsigned long long pk = 0;
#pragma unroll
        for (int r = 0; r < 4; ++r)
          pk |= (unsigned long long)f2b(aa[mf][nf][r]) << (16 * r);
        *(unsigned long long*)(AS + n * 256 + (((e0 >> 3) ^ (n & 15)) << 4) + ((e0 & 7) << 1)) = pk;
      }
    __syncthreads();

    // Phase D: out-GEMM, D[c_out][n], direct global stores.
    // (AS re-written next iter only after that iter's post-B barrier.)
    f32x4 oa[4];
#pragma unroll
    for (int nf = 0; nf < 4; ++nf) oa[nf] = (f32x4){0.f, 0.f, 0.f, 0.f};
#pragma unroll
    for (int ks = 0; ks < 4; ++ks)
#pragma unroll
      for (int nf = 0; nf < 4; ++nf) {
        const int n = nf * 16 + l15;
        const bf16x8 af = *(const bf16x8*)(AS + n * 256 + (((ks * 4 + l4) ^ (n & 15)) << 4));
        oa[nf] = MFMA(wo[ks], af, oa[nf]);
      }
#pragma unroll
    for (int nf = 0; nf < 4; ++nf)
#pragma unroll
      for (int r = 0; r < 4; ++r) {
        const int c = w * 16 + l4 * 4 + r;
        ob[(size_t)c * NN + n0 + nf * 16 + l15] = oa[nf][r] + bo_r[r];
      }
  }
}

// ---------------------------------------------------------------------------
extern "C" void kernel_launch(void* const* d_in, const int* in_sizes, int n_in,
                              void* d_out, int out_size, void* d_ws, size_t ws_size,
                              hipStream_t stream) {
  const float* x  = (const float*)d_in[0];
  const float* Wq = (const float*)d_in[1];
  const float* bq = (const float*)d_in[2];
  const float* Wk = (const float*)d_in[3];
  const float* bk = (const float*)d_in[4];
  const float* Wv = (const float*)d_in[5];
  const float* bv = (const float*)d_in[6];
  const float* gK = (const float*)d_in[7];
  const float* bK = (const float*)d_in[8];
  const float* gV = (const float*)d_in[9];
  const float* bV = (const float*)d_in[10];
  const float* Wo = (const float*)d_in[11];
  const float* bo = (const float*)d_in[12];
  float* out = (float*)d_out;

  char* ws = (char*)d_ws;
  float* kvp = (float*)ws;                                   // 8*128*4096 f32 = 16 MB
  float* p2  = kvp + (size_t)BB * NC1 * 4096;                // 256*1024 f32 = 1 MB
  unsigned short* kvTb = (unsigned short*)(p2 + 256 * 1024); // 64 KB
  unsigned short* Wb = kvTb + (size_t)BB * HH * 1024;        // 128 KB
  unsigned short* xF = Wb + 65536;                           // 8*16*16384*8 bf16 = 32 MB
  const unsigned short* Wqb = Wb;
  const unsigned short* Wkb = Wb + 16384;
  const unsigned short* Wvb = Wb + 32768;
  const unsigned short* Wob = Wb + 49152;

  (void)hipFuncSetAttribute(reinterpret_cast<const void*>(k_xpose),
                            hipFuncAttributeMaxDynamicSharedMemorySize, 131072);
  (void)hipFuncSetAttribute(reinterpret_cast<const void*>(k_fuse1),
                            hipFuncAttributeMaxDynamicSharedMemorySize, 36864);
  (void)hipFuncSetAttribute(reinterpret_cast<const void*>(k_pass2),
                            hipFuncAttributeMaxDynamicSharedMemorySize, 32768);

  k_prep<<<256, 256, 0, stream>>>(Wq, Wk, Wv, Wo, Wb);

  k_xpose<<<dim3(NN / 512, BB), 1024, 131072, stream>>>(x, xF);

  k_fuse1<<<dim3(NC1, BB), 512, 36864, stream>>>(
      xF, Wkb, Wvb, bk, bv, gK, bK, gV, bV, kvp);

  k_reduceA<<<256, 256, 0, stream>>>(kvp, p2);

  const float scale = 1.0f / (5.65685424949238f * 16384.0f);  // 1/(sqrt(32)*N)
  k_reduceB<<<32, 256, 0, stream>>>(p2, kvTb, scale);

  k_pass2<<<dim3(NC2, BB), 512, 32768, stream>>>(
      xF, Wqb, bq, kvTb, Wob, bo, out);
}

// Round 15
// 85.971 us; speedup vs baseline: 1.2394x; 1.2394x over previous
//
#include <hip/hip_runtime.h>
#include <cmath>

#define BB 8
#define CC 128
#define NN 16384
#define HH 4
#define NBK 64                   // fuse1/pass2 blocks per batch (256 n each)
#define SX 272                   // XT row stride in bytes (17 x 16B, bank-skewed)

typedef __attribute__((ext_vector_type(8))) short bf16x8;
typedef __attribute__((ext_vector_type(4))) float f32x4;

#define MFMA(a, b, c) __builtin_amdgcn_mfma_f32_16x16x32_bf16(a, b, c, 0, 0, 0)

// fp32 -> bf16 (RNE)
__device__ __forceinline__ unsigned short f2b(float f) {
  union { float f; unsigned u; } v; v.f = f;
  unsigned r = v.u + 0x7FFFu + ((v.u >> 16) & 1u);
  return (unsigned short)(r >> 16);
}

// XT addressing: [n][c] bf16, SX-byte rows, 16B block index = c/8, XOR'd with (n>>2)&7
__device__ __forceinline__ int xt_addr(int n, int cblk) {
  return n * SX + ((cblk ^ ((n >> 2) & 7)) << 4);
}
// KT/VT layout: [c][n] bf16, 144 B/row stride, XOR-swizzle on 16B blocks
__device__ __forceinline__ int kt_byte(int c, int n) {
  return c * 144 + ((((n >> 3) ^ (c & 7)) << 4) | ((n & 7) << 1));
}

// ---------------------------------------------------------------------------
// K0: convert Wq,Wk,Wv,Wo fp32[128][128] -> bf16 (same layout)
// ---------------------------------------------------------------------------
__global__ void k_prep(const float* __restrict__ Wq, const float* __restrict__ Wk,
                       const float* __restrict__ Wv, const float* __restrict__ Wo,
                       unsigned short* __restrict__ Wb) {
  const int idx = blockIdx.x * 256 + threadIdx.x;   // < 65536
  const int which = idx >> 14;
  const float* src = (which == 0) ? Wq : (which == 1) ? Wk : (which == 2) ? Wv : Wo;
  Wb[idx] = f2b(src[idx & 16383]);
}

// ---------------------------------------------------------------------------
// K1 (R10 structure + 4 dedicated Q-waves, 768 thr = 12 waves):
// per (b, 256-n chunk), 2 tiles of 128 n:
//   stage x -> XT (waves 0..7: 1 c-block; waves 8..11: 2 c-blocks)
//   2 sub-tiles of 64 n:
//     waves 0..7: K/V proj MFMA + per-head LN -> KT/VT
//     waves 8..11: Q proj MFMA (head = w-8) -> global qg (pre-fragmented)
//     sync; waves 0..7: partial K^T V MFMA; sync
// qg layout: [b][h][dc(0..3)][n][8 d] bf16 -- pass2 B-frag = one 16B load.
// LDS: XT 34816 | KT 18432 | VT 18432 = 71680 -> 2 blocks/CU, 6 waves/SIMD
// ---------------------------------------------------------------------------
__global__ __launch_bounds__(768, 4)
void k_fuse1(const float* __restrict__ x,
             const unsigned short* __restrict__ Wqb, const float* __restrict__ bq,
             const unsigned short* __restrict__ Wkb, const unsigned short* __restrict__ Wvb,
             const float* __restrict__ bk, const float* __restrict__ bv,
             const float* __restrict__ gK, const float* __restrict__ bK,
             const float* __restrict__ gV, const float* __restrict__ bV,
             unsigned short* __restrict__ qg, float* __restrict__ kvp) {
  extern __shared__ char lds[];
  char* XT = lds;                       // 34816 B (128 rows x 272)
  char* KT = lds + 34816;               // 18432 B
  char* VT = lds + 53248;               // 18432 B
  float* KVS = (float*)lds;             // 32 KB, overlays XT at the end

  const int tid = threadIdx.x;
  const int lane = tid & 63;
  const int w = tid >> 6;               // 0..11
  const int b = blockIdx.y;
  const int bx = blockIdx.x;
  const int l15 = lane & 15, l4 = lane >> 4;

  const bool isq = (w >= 8);
  const int ph = isq ? (w - 8) : (w >> 1);   // head (proj)
  const int pp = isq ? 0 : (w & 1);          // 0=K, 1=V (K/V waves)
  const int kh = w >> 1, khalf = w & 1;      // kv roles (waves 0..7)

  // W fragments: row = l15 (c_out within head-slice), k = ks*32 + l4*8 + j
  const unsigned short* Wsrc = isq ? Wqb : (pp ? Wvb : Wkb);
  bf16x8 wf[2][4];
#pragma unroll
  for (int mf = 0; mf < 2; ++mf)
#pragma unroll
    for (int ks = 0; ks < 4; ++ks)
      wf[mf][ks] = *(const bf16x8*)(Wsrc + (ph * 32 + mf * 16 + l15) * 128 + ks * 32 + l4 * 8);

  float bias[2][4], gam[2][4], bet[2][4];
  {
    const float* bsrc = isq ? bq : (pp ? bv : bk);
    const float* gsrc = (!isq && pp) ? gV : gK;   // unused by Q waves
    const float* esrc = (!isq && pp) ? bV : bK;
#pragma unroll
    for (int mf = 0; mf < 2; ++mf)
#pragma unroll
      for (int r = 0; r < 4; ++r) {
        const int cg = ph * 32 + mf * 16 + l4 * 4 + r;
        bias[mf][r] = bsrc[cg]; gam[mf][r] = gsrc[cg]; bet[mf][r] = esrc[cg];
      }
  }

  f32x4 kvacc[2][2];
#pragma unroll
  for (int i = 0; i < 2; ++i)
#pragma unroll
    for (int j = 0; j < 2; ++j) kvacc[i][j] = (f32x4){0.f, 0.f, 0.f, 0.f};

  // q store base for this wave's head (waves 8..11): chunk = (b*H + ph)*4 + dc
  unsigned short* qh = qg + ((size_t)(b * HH + ph) * 4) * NN * 8;

  for (int ot = 0; ot < 2; ++ot) {
    const int n0 = (bx * 2 + ot) * 128;

    // Phase 1: stage 128c x 128n of x -> XT.
    // waves 0..7: c-block w; waves 8..11: c-blocks 8+2(w-8), 9+2(w-8).
    {
      const int cb0 = isq ? (8 + (w - 8) * 2) : w;
      const int ng = isq ? 2 : 1;
      for (int g = 0; g < ng; ++g) {
        const int cb = cb0 + g;
        const float* xb = x + ((size_t)b * CC + cb * 8) * NN + n0 + lane * 2;
        float2 va[8];
#pragma unroll
        for (int cc = 0; cc < 8; ++cc) va[cc] = *(const float2*)(xb + (size_t)cc * NN);
#pragma unroll
        for (int j = 0; j < 2; ++j) {
          const int n = lane * 2 + j;
          bf16x8 pk;
#pragma unroll
          for (int cc = 0; cc < 8; ++cc)
            ((unsigned short*)&pk)[cc] = f2b(j ? va[cc].y : va[cc].x);
          *(bf16x8*)(XT + n * SX + ((cb ^ ((n >> 2) & 7)) << 4)) = pk;
        }
      }
    }
    __syncthreads();

    // Phase 2: two 64-n sub-tiles
    for (int t = 0; t < 2; ++t) {
      const int nbase = t * 64;
      char* DST = pp ? VT : KT;
#pragma unroll
      for (int nf = 0; nf < 4; ++nf) {
        const int n = nbase + nf * 16 + l15;
        f32x4 a0 = (f32x4){0.f, 0.f, 0.f, 0.f}, a1 = (f32x4){0.f, 0.f, 0.f, 0.f};
#pragma unroll
        for (int ks = 0; ks < 4; ++ks) {
          const bf16x8 xf = *(const bf16x8*)(XT + xt_addr(n, ks * 4 + l4));
          a0 = MFMA(wf[0][ks], xf, a0);
          a1 = MFMA(wf[1][ks], xf, a1);
        }
#pragma unroll
        for (int r = 0; r < 4; ++r) { a0[r] += bias[0][r]; a1[r] += bias[1][r]; }

        if (!isq) {
          // per-head LN over 32 channels + stage bf16 to KT/VT
          float s = 0.f, ss = 0.f;
#pragma unroll
          for (int r = 0; r < 4; ++r) {
            s += a0[r] + a1[r];
            ss += a0[r] * a0[r] + a1[r] * a1[r];
          }
          s += __shfl_xor(s, 16); ss += __shfl_xor(ss, 16);
          s += __shfl_xor(s, 32); ss += __shfl_xor(ss, 32);
          const float mu = s * (1.f / 32.f);
          const float var = ss * (1.f / 32.f) - mu * mu;
          const float rstd = rsqrtf(var + 1e-5f);
          const int nloc = nf * 16 + l15;
#pragma unroll
          for (int r = 0; r < 4; ++r) {
            const int c0k = ph * 32 + l4 * 4 + r;
            *(unsigned short*)(DST + kt_byte(c0k, nloc)) =
                f2b((a0[r] - mu) * rstd * gam[0][r] + bet[0][r]);
            const int c1k = ph * 32 + 16 + l4 * 4 + r;
            *(unsigned short*)(DST + kt_byte(c1k, nloc)) =
                f2b((a1[r] - mu) * rstd * gam[1][r] + bet[1][r]);
          }
        } else {
          // q -> global, pre-fragmented: dc = mf*2 + (l4>>1), d%8 = (l4&1)*4 + r
          const int gn = n0 + n;
#pragma unroll
          for (int mf = 0; mf < 2; ++mf) {
            const f32x4 aa = mf ? a1 : a0;
            unsigned long long pk = 0;
#pragma unroll
            for (int r = 0; r < 4; ++r)
              pk |= (unsigned long long)f2b(aa[r]) << (16 * r);
            *(unsigned long long*)(qh + ((size_t)(mf * 2 + (l4 >> 1)) * NN + gn) * 8 +
                                   (l4 & 1) * 4) = pk;
          }
        }
      }
      __syncthreads();

      // kv partial += K^T V (waves 0..7 only), over this wave's 32-n half
      if (!isq) {
#pragma unroll
        for (int mf = 0; mf < 2; ++mf) {
          const int ck = kh * 32 + mf * 16 + l15;
          const bf16x8 ka = *(const bf16x8*)(KT + ck * 144 + (((khalf * 4 + l4) ^ (ck & 7)) << 4));
#pragma unroll
          for (int ef = 0; ef < 2; ++ef) {
            const int cv = kh * 32 + ef * 16 + l15;
            const bf16x8 vb = *(const bf16x8*)(VT + cv * 144 + (((khalf * 4 + l4) ^ (cv & 7)) << 4));
            kvacc[mf][ef] = MFMA(ka, vb, kvacc[mf][ef]);
          }
        }
      }
      __syncthreads();   // KT/VT (and XT on last t) safe to overwrite
    }
  }

  // epilogue: waves 0..7 stage kvacc -> KVS[w][1024] (overlays dead XT)
  if (!isq) {
#pragma unroll
    for (int mf = 0; mf < 2; ++mf)
#pragma unroll
      for (int ef = 0; ef < 2; ++ef)
#pragma unroll
        for (int r = 0; r < 4; ++r) {
          const int d = mf * 16 + l4 * 4 + r, e = ef * 16 + l15;
          KVS[w * 1024 + d * 32 + e] = kvacc[mf][ef][r];
        }
  }
  __syncthreads();
  if (tid < 512) {
    float* og = kvp + ((size_t)(b * NBK + bx)) * 8192;
#pragma unroll
    for (int i = 0; i < 4; ++i) {
      const int off = i * 2048 + tid * 4;
      *(f32x4*)(og + off) = *(const f32x4*)(KVS + off);
    }
  }
}

// ---------------------------------------------------------------------------
// K2a: partial reduce: block (b,h,s): sum over 8 bx and the 2 khalf slots
// ---------------------------------------------------------------------------
__global__ void k_reduceA(const float* __restrict__ kvp, float* __restrict__ p2) {
  const int blk = blockIdx.x;           // (b*4+h)*8 + s, 256 blocks
  const int s = blk & 7, h = (blk >> 3) & 3, b = blk >> 5;
  const int t = threadIdx.x;            // 256 threads, float4 each
  f32x4 acc = (f32x4){0.f, 0.f, 0.f, 0.f};
  for (int i = 0; i < 8; ++i) {
    const int bx = s * 8 + i;
    const float* base = kvp + ((size_t)(b * NBK + bx)) * 8192 + t * 4;
    acc += *(const f32x4*)(base + (2 * h) * 1024);
    acc += *(const f32x4*)(base + (2 * h + 1) * 1024);
  }
  *(f32x4*)(p2 + (size_t)blk * 1024 + t * 4) = acc;
}

// ---------------------------------------------------------------------------
// K2b: final reduce over s, scale, store kvT[b][h][e][d] bf16
// ---------------------------------------------------------------------------
__global__ void k_reduceB(const float* __restrict__ p2, unsigned short* __restrict__ kvT,
                          const float scale) {
  const int bh = blockIdx.x;            // b*4+h, 32 blocks
  const int t = threadIdx.x;            // 256 threads
  f32x4 acc = (f32x4){0.f, 0.f, 0.f, 0.f};
  for (int s = 0; s < 8; ++s)
    acc += *(const f32x4*)(p2 + ((size_t)bh * 8 + s) * 1024 + t * 4);
#pragma unroll
  for (int j = 0; j < 4; ++j) {
    const int i = t * 4 + j;
    const int d = i >> 5, e = i & 31;
    kvT[(size_t)bh * 1024 + e * 32 + d] = f2b(acc[j] * scale);
  }
}

// ---------------------------------------------------------------------------
// K3 (R9-measured slim pass2, ~13 us): attn (q @ kv) + out-GEMM. No x read,
// no q-GEMM: q B-fragments load directly from pre-fragmented qg (16B/lane).
// LDS: AS double buffer 2 x 16384 = 32768 -> 4 blocks/CU
// ---------------------------------------------------------------------------
__global__ __launch_bounds__(512, 6)
void k_pass2(const unsigned short* __restrict__ qg,
             const unsigned short* __restrict__ kvT,
             const unsigned short* __restrict__ Wob, const float* __restrict__ bo,
             float* __restrict__ out) {
  extern __shared__ char lds[];         // 2 x 16384 AS buffers

  const int tid = threadIdx.x;
  const int lane = tid & 63;
  const int w = tid >> 6;
  const int b = blockIdx.y;
  const int bx = blockIdx.x;
  const int l15 = lane & 15, l4 = lane >> 4;
  const int h = w >> 1, half = w & 1;

  // kv A-fragments (row = e, k = d) from global bf16 kvT[b][h][e][d]
  bf16x8 kvf[2];
#pragma unroll
  for (int mf = 0; mf < 2; ++mf)
    kvf[mf] = *(const bf16x8*)(kvT + (((size_t)b * HH + h) * 32 + mf * 16 + l15) * 32 + l4 * 8);
  bf16x8 wo[4];
#pragma unroll
  for (int ks = 0; ks < 4; ++ks)
    wo[ks] = *(const bf16x8*)(Wob + (w * 16 + l15) * 128 + ks * 32 + l4 * 8);
  float bo_r[4];
#pragma unroll
  for (int r = 0; r < 4; ++r) bo_r[r] = bo[w * 16 + l4 * 4 + r];

  // q B-fragment base for this lane: chunk = (b*H + h)*4 + l4
  const unsigned short* qbase = qg + (((size_t)(b * HH + h) * 4 + l4) * NN) * 8;
  float* ob = out + (size_t)b * CC * NN;

  for (int it = 0; it < 4; ++it) {
    const int n0 = bx * 256 + it * 64;
    char* AS = lds + (it & 1) * 16384;

    // attn: D[e][n] = kv(as A) * q(as B), per (head, n-half)
    bf16x8 qf[2];
#pragma unroll
    for (int nf = 0; nf < 2; ++nf)
      qf[nf] = *(const bf16x8*)(qbase + (size_t)(n0 + half * 32 + nf * 16 + l15) * 8);
    f32x4 aa[2][2];
#pragma unroll
    for (int i = 0; i < 2; ++i)
#pragma unroll
      for (int j = 0; j < 2; ++j) aa[i][j] = (f32x4){0.f, 0.f, 0.f, 0.f};
#pragma unroll
    for (int mf = 0; mf < 2; ++mf)
#pragma unroll
      for (int nf = 0; nf < 2; ++nf) aa[mf][nf] = MFMA(kvf[mf], qf[nf], aa[mf][nf]);
#pragma unroll
    for (int mf = 0; mf < 2; ++mf)
#pragma unroll
      for (int nf = 0; nf < 2; ++nf) {
        const int n = half * 32 + nf * 16 + l15;
        const int e0 = h * 32 + mf * 16 + l4 * 4;
        unsigned long long pk = 0;
#pragma unroll
        for (int r = 0; r < 4; ++r)
          pk |= (unsigned long long)f2b(aa[mf][nf][r]) << (16 * r);
        *(unsigned long long*)(AS + n * 256 + (((e0 >> 3) ^ (n & 15)) << 4) + ((e0 & 7) << 1)) = pk;
      }
    __syncthreads();   // AS[it&1] writes visible; AS double-buffered across iters

    // out-GEMM, D[c_out][n], direct global stores
    f32x4 oa[4];
#pragma unroll
    for (int nf = 0; nf < 4; ++nf) oa[nf] = (f32x4){0.f, 0.f, 0.f, 0.f};
#pragma unroll
    for (int ks = 0; ks < 4; ++ks)
#pragma unroll
      for (int nf = 0; nf < 4; ++nf) {
        const int n = nf * 16 + l15;
        const bf16x8 af = *(const bf16x8*)(AS + n * 256 + (((ks * 4 + l4) ^ (n & 15)) << 4));
        oa[nf] = MFMA(wo[ks], af, oa[nf]);
      }
#pragma unroll
    for (int nf = 0; nf < 4; ++nf)
#pragma unroll
      for (int r = 0; r < 4; ++r) {
        const int c = w * 16 + l4 * 4 + r;
        ob[(size_t)c * NN + n0 + nf * 16 + l15] = oa[nf][r] + bo_r[r];
      }
  }
}

// ---------------------------------------------------------------------------
extern "C" void kernel_launch(void* const* d_in, const int* in_sizes, int n_in,
                              void* d_out, int out_size, void* d_ws, size_t ws_size,
                              hipStream_t stream) {
  const float* x  = (const float*)d_in[0];
  const float* Wq = (const float*)d_in[1];
  const float* bq = (const float*)d_in[2];
  const float* Wk = (const float*)d_in[3];
  const float* bk = (const float*)d_in[4];
  const float* Wv = (const float*)d_in[5];
  const float* bv = (const float*)d_in[6];
  const float* gK = (const float*)d_in[7];
  const float* bK = (const float*)d_in[8];
  const float* gV = (const float*)d_in[9];
  const float* bV = (const float*)d_in[10];
  const float* Wo = (const float*)d_in[11];
  const float* bo = (const float*)d_in[12];
  float* out = (float*)d_out;

  char* ws = (char*)d_ws;
  float* kvp = (float*)ws;                                   // 8*64*8192 f32 = 16 MB
  float* p2  = kvp + (size_t)BB * NBK * 8192;                // 256*1024 f32 = 1 MB
  unsigned short* kvTb = (unsigned short*)(p2 + 256 * 1024); // 64 KB
  unsigned short* Wb = kvTb + (size_t)BB * HH * 1024;        // 128 KB
  unsigned short* qg = Wb + 65536;                           // 8*16*16384*8 bf16 = 32 MB
  const unsigned short* Wqb = Wb;
  const unsigned short* Wkb = Wb + 16384;
  const unsigned short* Wvb = Wb + 32768;
  const unsigned short* Wob = Wb + 49152;

  (void)hipFuncSetAttribute(reinterpret_cast<const void*>(k_fuse1),
                            hipFuncAttributeMaxDynamicSharedMemorySize, 71680);
  (void)hipFuncSetAttribute(reinterpret_cast<const void*>(k_pass2),
                            hipFuncAttributeMaxDynamicSharedMemorySize, 32768);

  k_prep<<<256, 256, 0, stream>>>(Wq, Wk, Wv, Wo, Wb);

  k_fuse1<<<dim3(NBK, BB), 768, 71680, stream>>>(
      x, Wqb, bq, Wkb, Wvb, bk, bv, gK, bK, gV, bV, qg, kvp);

  k_reduceA<<<256, 256, 0, stream>>>(kvp, p2);

  const float scale = 1.0f / (5.65685424949238f * 16384.0f);  // 1/(sqrt(32)*N)
  k_reduceB<<<32, 256, 0, stream>>>(p2, kvTb, scale);

  k_pass2<<<dim3(NBK, BB), 512, 32768, stream>>>(
      qg, kvTb, Wob, bo, out);
}

// Round 16
// 71.011 us; speedup vs baseline: 1.5004x; 1.2107x over previous
//
#include <hip/hip_runtime.h>
#include <cmath>

#define BB 8
#define CC 128
#define NN 16384
#define HH 4
#define NBK 64                   // fuse1/pass2 blocks per batch (256 n each)
#define SX 272                   // XT row stride in bytes (17 x 16B, bank-skewed)

typedef __attribute__((ext_vector_type(8))) short bf16x8;
typedef __attribute__((ext_vector_type(4))) float f32x4;

#define MFMA(a, b, c) __builtin_amdgcn_mfma_f32_16x16x32_bf16(a, b, c, 0, 0, 0)

// fp32 -> bf16 (RNE)
__device__ __forceinline__ unsigned short f2b(float f) {
  union { float f; unsigned u; } v; v.f = f;
  unsigned r = v.u + 0x7FFFu + ((v.u >> 16) & 1u);
  return (unsigned short)(r >> 16);
}

// XT addressing: [n][c] bf16, SX-byte rows, 16B block index = c/8, XOR'd with (n>>2)&7
__device__ __forceinline__ int xt_addr(int n, int cblk) {
  return n * SX + ((cblk ^ ((n >> 2) & 7)) << 4);
}
// KT/VT layout: [c][n] bf16, 144 B/row stride, XOR-swizzle on 16B blocks
__device__ __forceinline__ int kt_byte(int c, int n) {
  return c * 144 + ((((n >> 3) ^ (c & 7)) << 4) | ((n & 7) << 1));
}

// ---------------------------------------------------------------------------
// K0: convert Wq,Wk,Wv,Wo fp32[128][128] -> bf16 (same layout)
// ---------------------------------------------------------------------------
__global__ void k_prep(const float* __restrict__ Wq, const float* __restrict__ Wk,
                       const float* __restrict__ Wv, const float* __restrict__ Wo,
                       unsigned short* __restrict__ Wb) {
  const int idx = blockIdx.x * 256 + threadIdx.x;   // < 65536
  const int which = idx >> 14;
  const float* src = (which == 0) ? Wq : (which == 1) ? Wk : (which == 2) ? Wv : Wo;
  Wb[idx] = f2b(src[idx & 16383]);
}

// ---------------------------------------------------------------------------
// K1 (proven R10 structure; epilogue pair-reduces khalf -> kvp 8 MB):
// per (b, 256-n chunk), 2 tiles of 128 n:
//   stage x -> XT (bf16 [n][c], 272-stride, 16B gathered stores)
//   2 sub-tiles of 64 n: K/V proj MFMA (per-nf) + per-head LN + partial K^T V
// Roles: proj (head = w>>1, K/V = w&1); kv (head = w>>1, 32-n half = w&1)
// LDS: XT 34816 | KT 18432 | VT 18432 = 71680 -> 2 blocks/CU
// ---------------------------------------------------------------------------
__global__ __launch_bounds__(512, 4)
void k_fuse1(const float* __restrict__ x,
             const unsigned short* __restrict__ Wkb, const unsigned short* __restrict__ Wvb,
             const float* __restrict__ bk, const float* __restrict__ bv,
             const float* __restrict__ gK, const float* __restrict__ bK,
             const float* __restrict__ gV, const float* __restrict__ bV,
             float* __restrict__ kvp) {
  extern __shared__ char lds[];
  char* XT = lds;                       // 34816 B (128 rows x 272)
  char* KT = lds + 34816;               // 18432 B
  char* VT = lds + 53248;               // 18432 B
  float* KVS = (float*)lds;             // 32 KB, overlays XT at the end

  const int tid = threadIdx.x;
  const int lane = tid & 63;
  const int w = tid >> 6;               // 0..7
  const int b = blockIdx.y;
  const int bx = blockIdx.x;
  const int l15 = lane & 15, l4 = lane >> 4;

  const int ph = w >> 1, pp = w & 1;    // proj: head, K/V
  const int kh = w >> 1, khalf = w & 1; // kv: head, 32-n half

  // W fragments: row = l15 (c_out), k = ks*32 + l4*8 + j
  const unsigned short* Wsrc = pp ? Wvb : Wkb;
  bf16x8 wf[2][4];
#pragma unroll
  for (int mf = 0; mf < 2; ++mf)
#pragma unroll
    for (int ks = 0; ks < 4; ++ks)
      wf[mf][ks] = *(const bf16x8*)(Wsrc + (ph * 32 + mf * 16 + l15) * 128 + ks * 32 + l4 * 8);

  float bias[2][4], gam[2][4], bet[2][4];
  {
    const float* bsrc = pp ? bv : bk;
    const float* gsrc = pp ? gV : gK;
    const float* esrc = pp ? bV : bK;
#pragma unroll
    for (int mf = 0; mf < 2; ++mf)
#pragma unroll
      for (int r = 0; r < 4; ++r) {
        const int cg = ph * 32 + mf * 16 + l4 * 4 + r;
        bias[mf][r] = bsrc[cg]; gam[mf][r] = gsrc[cg]; bet[mf][r] = esrc[cg];
      }
  }

  f32x4 kvacc[2][2];
#pragma unroll
  for (int i = 0; i < 2; ++i)
#pragma unroll
    for (int j = 0; j < 2; ++j) kvacc[i][j] = (f32x4){0.f, 0.f, 0.f, 0.f};

  for (int ot = 0; ot < 2; ++ot) {
    const int n0 = (bx * 2 + ot) * 128;

    // Phase 1: stage 128c x 128n of x -> XT. Thread: 2 groups x 8 c-rows x float2.
#pragma unroll
    for (int g = 0; g < 2; ++g) {
      const int cb = w * 2 + g;          // c-block 0..15
      const float* xb = x + ((size_t)b * CC + cb * 8) * NN + n0 + lane * 2;
      float2 va[8];
#pragma unroll
      for (int cc = 0; cc < 8; ++cc) va[cc] = *(const float2*)(xb + (size_t)cc * NN);
#pragma unroll
      for (int j = 0; j < 2; ++j) {
        const int n = lane * 2 + j;
        bf16x8 pk;
#pragma unroll
        for (int cc = 0; cc < 8; ++cc)
          ((unsigned short*)&pk)[cc] = f2b(j ? va[cc].y : va[cc].x);
        *(bf16x8*)(XT + n * SX + ((cb ^ ((n >> 2) & 7)) << 4)) = pk;
      }
    }
    __syncthreads();

    // Phase 2: two 64-n sub-tiles: proj per-nf (low reg pressure) + LN + kv
    for (int t = 0; t < 2; ++t) {
      const int nbase = t * 64;
      char* DST = pp ? VT : KT;
#pragma unroll
      for (int nf = 0; nf < 4; ++nf) {
        const int n = nbase + nf * 16 + l15;
        f32x4 a0 = (f32x4){0.f, 0.f, 0.f, 0.f}, a1 = (f32x4){0.f, 0.f, 0.f, 0.f};
#pragma unroll
        for (int ks = 0; ks < 4; ++ks) {
          const bf16x8 xf = *(const bf16x8*)(XT + xt_addr(n, ks * 4 + l4));
          a0 = MFMA(wf[0][ks], xf, a0);
          a1 = MFMA(wf[1][ks], xf, a1);
        }
#pragma unroll
        for (int r = 0; r < 4; ++r) { a0[r] += bias[0][r]; a1[r] += bias[1][r]; }
        float s = 0.f, ss = 0.f;
#pragma unroll
        for (int r = 0; r < 4; ++r) {
          s += a0[r] + a1[r];
          ss += a0[r] * a0[r] + a1[r] * a1[r];
        }
        s += __shfl_xor(s, 16); ss += __shfl_xor(ss, 16);
        s += __shfl_xor(s, 32); ss += __shfl_xor(ss, 32);
        const float mu = s * (1.f / 32.f);
        const float var = ss * (1.f / 32.f) - mu * mu;
        const float rstd = rsqrtf(var + 1e-5f);
        const int nloc = nf * 16 + l15;
#pragma unroll
        for (int r = 0; r < 4; ++r) {
          const int c0k = ph * 32 + l4 * 4 + r;
          *(unsigned short*)(DST + kt_byte(c0k, nloc)) =
              f2b((a0[r] - mu) * rstd * gam[0][r] + bet[0][r]);
          const int c1k = ph * 32 + 16 + l4 * 4 + r;
          *(unsigned short*)(DST + kt_byte(c1k, nloc)) =
              f2b((a1[r] - mu) * rstd * gam[1][r] + bet[1][r]);
        }
      }
      __syncthreads();

      // kv partial += K^T V over this wave's 32-n half of the 64-n sub-tile
#pragma unroll
      for (int mf = 0; mf < 2; ++mf) {
        const int ck = kh * 32 + mf * 16 + l15;
        const bf16x8 ka = *(const bf16x8*)(KT + ck * 144 + (((khalf * 4 + l4) ^ (ck & 7)) << 4));
#pragma unroll
        for (int ef = 0; ef < 2; ++ef) {
          const int cv = kh * 32 + ef * 16 + l15;
          const bf16x8 vb = *(const bf16x8*)(VT + cv * 144 + (((khalf * 4 + l4) ^ (cv & 7)) << 4));
          kvacc[mf][ef] = MFMA(ka, vb, kvacc[mf][ef]);
        }
      }
      __syncthreads();   // KT/VT (and XT on last t) safe to overwrite
    }
  }

  // epilogue: KVS[w][1024] (overlays dead XT), pair-reduce khalf, 16 KB dump
#pragma unroll
  for (int mf = 0; mf < 2; ++mf)
#pragma unroll
    for (int ef = 0; ef < 2; ++ef)
#pragma unroll
      for (int r = 0; r < 4; ++r) {
        const int d = mf * 16 + l4 * 4 + r, e = ef * 16 + l15;
        KVS[w * 1024 + d * 32 + e] = kvacc[mf][ef][r];
      }
  __syncthreads();
  {
    float* og = kvp + ((size_t)(b * NBK + bx)) * 4096;
#pragma unroll
    for (int i = 0; i < 2; ++i) {
      const int off = i * 2048 + tid * 4;          // 0..4095 = h*1024 + q
      const int h = off >> 10, q = off & 1023;
      const f32x4 v0 = *(const f32x4*)(KVS + (2 * h) * 1024 + q);
      const f32x4 v1 = *(const f32x4*)(KVS + (2 * h + 1) * 1024 + q);
      *(f32x4*)(og + off) = v0 + v1;
    }
  }
}

// ---------------------------------------------------------------------------
// K2: single-stage kv reduce over 64 bx slots (fixed order), scale,
//     store kvT[b][h][e][d] bf16.  32 blocks x 1024 thr, coalesced reads.
// ---------------------------------------------------------------------------
__global__ void k_reduce(const float* __restrict__ kvp, unsigned short* __restrict__ kvT,
                         const float scale) {
  const int bh = blockIdx.x;            // b*4+h, 32 blocks
  const int h = bh & 3, b = bh >> 2;
  const int i = threadIdx.x;            // 0..1023 -> d*32+e
  const float* base = kvp + (size_t)(b * NBK) * 4096 + h * 1024 + i;
  float acc = 0.f;
  for (int bx = 0; bx < NBK; ++bx) acc += base[(size_t)bx * 4096];
  const int d = i >> 5, e = i & 31;
  kvT[(size_t)bh * 1024 + e * 32 + d] = f2b(acc * scale);
}

// ---------------------------------------------------------------------------
// K3 (proven R7/R10 structure): Q proj + attn + out-GEMM, double-buffered x
// staging from regs, amortized fragments, direct global stores.
// LDS: XT0 17408 | XT1 17408 | QS 16384 | AS 16384 = 67584 -> 2 blocks/CU
// ---------------------------------------------------------------------------
__global__ __launch_bounds__(512, 4)
void k_pass2(const float* __restrict__ x,
             const unsigned short* __restrict__ Wqb, const float* __restrict__ bq,
             const unsigned short* __restrict__ kvT,
             const unsigned short* __restrict__ Wob, const float* __restrict__ bo,
             float* __restrict__ out) {
  extern __shared__ char lds[];
  char* QS = lds + 34816;    // 16384  q as [n][c]
  char* AS = lds + 51200;    // 16384  attn out as [n][c']

  const int tid = threadIdx.x;
  const int lane = tid & 63;
  const int w = tid >> 6;
  const int b = blockIdx.y;
  const int l15 = lane & 15, l4 = lane >> 4;
  const int h = w >> 1, half = w & 1;

  // kv A-fragments (row = e, k = d) from global bf16 kvT[b][h][e][d]
  bf16x8 kvf[2];
#pragma unroll
  for (int mf = 0; mf < 2; ++mf)
    kvf[mf] = *(const bf16x8*)(kvT + (((size_t)b * HH + h) * 32 + mf * 16 + l15) * 32 + l4 * 8);
  bf16x8 wq[4], wo[4];
#pragma unroll
  for (int ks = 0; ks < 4; ++ks) {
    wq[ks] = *(const bf16x8*)(Wqb + (w * 16 + l15) * 128 + ks * 32 + l4 * 8);
    wo[ks] = *(const bf16x8*)(Wob + (w * 16 + l15) * 128 + ks * 32 + l4 * 8);
  }
  float bq_r[4], bo_r[4];
#pragma unroll
  for (int r = 0; r < 4; ++r) {
    bq_r[r] = bq[w * 16 + l4 * 4 + r];
    bo_r[r] = bo[w * 16 + l4 * 4 + r];
  }

  const int half2 = lane >> 5;
  const int cb2 = w * 2 + half2;        // c-block 0..15
  const int nn = (lane & 31) * 2;
  const float* xrow = x + ((size_t)b * CC + cb2 * 8) * NN + blockIdx.x * 256 + nn;
  float* ob = out + (size_t)b * CC * NN;

  float2 rx[8];
#pragma unroll
  for (int cc = 0; cc < 8; ++cc) rx[cc] = *(const float2*)(xrow + (size_t)cc * NN);

  for (int it = 0; it < 4; ++it) {
    const int n0 = blockIdx.x * 256 + it * 64;
    char* XT = (it & 1) ? (lds + 17408) : lds;

    // stage tile from regs + prefetch next
#pragma unroll
    for (int j = 0; j < 2; ++j) {
      const int n = nn + j;
      bf16x8 pk;
#pragma unroll
      for (int cc = 0; cc < 8; ++cc)
        ((unsigned short*)&pk)[cc] = f2b(j ? rx[cc].y : rx[cc].x);
      *(bf16x8*)(XT + n * SX + ((cb2 ^ ((n >> 2) & 7)) << 4)) = pk;
    }
    if (it < 3) {
      const float* xn = xrow + (it + 1) * 64;
#pragma unroll
      for (int cc = 0; cc < 8; ++cc) rx[cc] = *(const float2*)(xn + (size_t)cc * NN);
    }
    __syncthreads();

    // Phase B: q-GEMM, D[c][n], c-slice = w*16
    f32x4 qa[4];
#pragma unroll
    for (int nf = 0; nf < 4; ++nf) qa[nf] = (f32x4){0.f, 0.f, 0.f, 0.f};
#pragma unroll
    for (int ks = 0; ks < 4; ++ks)
#pragma unroll
      for (int nf = 0; nf < 4; ++nf) {
        const int n = nf * 16 + l15;
        const bf16x8 xf = *(const bf16x8*)(XT + xt_addr(n, ks * 4 + l4));
        qa[nf] = MFMA(wq[ks], xf, qa[nf]);
      }
#pragma unroll
    for (int nf = 0; nf < 4; ++nf) {
      const int n = nf * 16 + l15;
      const int c0 = w * 16 + l4 * 4;
      unsigned long long pk = 0;
#pragma unroll
      for (int r = 0; r < 4; ++r)
        pk |= (unsigned long long)f2b(qa[nf][r] + bq_r[r]) << (16 * r);
      *(unsigned long long*)(QS + n * 256 + (((c0 >> 3) ^ (n & 15)) << 4) + ((c0 & 7) << 1)) = pk;
    }
    __syncthreads();

    // Phase C: attn D[e][n] = kv(as A) * q(as B), per (head, n-half)
    f32x4 aa[2][2];
#pragma unroll
    for (int i = 0; i < 2; ++i)
#pragma unroll
      for (int j = 0; j < 2; ++j) aa[i][j] = (f32x4){0.f, 0.f, 0.f, 0.f};
    bf16x8 qf[2];
#pragma unroll
    for (int nf = 0; nf < 2; ++nf) {
      const int n = half * 32 + nf * 16 + l15;
      const int cq = h * 32 + l4 * 8;
      qf[nf] = *(const bf16x8*)(QS + n * 256 + ((((cq >> 3)) ^ (n & 15)) << 4));
    }
#pragma unroll
    for (int mf = 0; mf < 2; ++mf)
#pragma unroll
      for (int nf = 0; nf < 2; ++nf) aa[mf][nf] = MFMA(kvf[mf], qf[nf], aa[mf][nf]);
#pragma unroll
    for (int mf = 0; mf < 2; ++mf)
#pragma unroll
      for (int nf = 0; nf < 2; ++nf) {
        const int n = half * 32 + nf * 16 + l15;
        const int e0 = h * 32 + mf * 16 + l4 * 4;
        unsigned long long pk = 0;
#pragma unroll
        for (int r = 0; r < 4; ++r)
          pk |= (unsigned long long)f2b(aa[mf][nf][r]) << (16 * r);
        *(unsigned long long*)(AS + n * 256 + (((e0 >> 3) ^ (n & 15)) << 4) + ((e0 & 7) << 1)) = pk;
      }
    __syncthreads();

    // Phase D: out-GEMM, D[c_out][n], direct global stores
    f32x4 oa[4];
#pragma unroll
    for (int nf = 0; nf < 4; ++nf) oa[nf] = (f32x4){0.f, 0.f, 0.f, 0.f};
#pragma unroll
    for (int ks = 0; ks < 4; ++ks)
#pragma unroll
      for (int nf = 0; nf < 4; ++nf) {
        const int n = nf * 16 + l15;
        const bf16x8 af = *(const bf16x8*)(AS + n * 256 + (((ks * 4 + l4) ^ (n & 15)) << 4));
        oa[nf] = MFMA(wo[ks], af, oa[nf]);
      }
#pragma unroll
    for (int nf = 0; nf < 4; ++nf)
#pragma unroll
      for (int r = 0; r < 4; ++r) {
        const int c = w * 16 + l4 * 4 + r;
        ob[(size_t)c * NN + n0 + nf * 16 + l15] = oa[nf][r] + bo_r[r];
      }
  }
}

// ---------------------------------------------------------------------------
extern "C" void kernel_launch(void* const* d_in, const int* in_sizes, int n_in,
                              void* d_out, int out_size, void* d_ws, size_t ws_size,
                              hipStream_t stream) {
  const float* x  = (const float*)d_in[0];
  const float* Wq = (const float*)d_in[1];
  const float* bq = (const float*)d_in[2];
  const float* Wk = (const float*)d_in[3];
  const float* bk = (const float*)d_in[4];
  const float* Wv = (const float*)d_in[5];
  const float* bv = (const float*)d_in[6];
  const float* gK = (const float*)d_in[7];
  const float* bK = (const float*)d_in[8];
  const float* gV = (const float*)d_in[9];
  const float* bV = (const float*)d_in[10];
  const float* Wo = (const float*)d_in[11];
  const float* bo = (const float*)d_in[12];
  float* out = (float*)d_out;

  char* ws = (char*)d_ws;
  float* kvp = (float*)ws;                                   // 8*64*4096 f32 = 8 MB
  unsigned short* kvTb = (unsigned short*)(ws + (size_t)BB * NBK * 4096 * 4); // 64 KB
  unsigned short* Wb = kvTb + (size_t)BB * HH * 1024;        // 128 KB
  const unsigned short* Wqb = Wb;
  const unsigned short* Wkb = Wb + 16384;
  const unsigned short* Wvb = Wb + 32768;
  const unsigned short* Wob = Wb + 49152;

  (void)hipFuncSetAttribute(reinterpret_cast<const void*>(k_fuse1),
                            hipFuncAttributeMaxDynamicSharedMemorySize, 71680);
  (void)hipFuncSetAttribute(reinterpret_cast<const void*>(k_pass2),
                            hipFuncAttributeMaxDynamicSharedMemorySize, 67584);

  k_prep<<<256, 256, 0, stream>>>(Wq, Wk, Wv, Wo, Wb);

  k_fuse1<<<dim3(NBK, BB), 512, 71680, stream>>>(
      x, Wkb, Wvb, bk, bv, gK, bK, gV, bV, kvp);

  const float scale = 1.0f / (5.65685424949238f * 16384.0f);  // 1/(sqrt(32)*N)
  k_reduce<<<32, 1024, 0, stream>>>(kvp, kvTb, scale);

  k_pass2<<<dim3(NBK, BB), 512, 67584, stream>>>(
      x, Wqb, bq, kvTb, Wob, bo, out);
}